// Round 1
// baseline (357.043 us; speedup 1.0000x reference)
//
#include <hip/hip_runtime.h>
#include <math.h>

// Problem constants
#define E_     64     // embedding dim == wavefront size
#define ND_    40     // diseases per visit
#define NM_    30     // medications per visit
#define NSTEP_ 31     // NM+1 decode steps
#define VO_    133    // VM+2 output vocab
#define J3_    192    // 3*E (GRU gates)
#define NROW_  8192   // B*S
#define RPB_   32     // rows per block in main kernel
#define SOS_   131    // VM

__device__ __forceinline__ float sigmoidf_(float x){ return 1.f/(1.f+__expf(-x)); }
__device__ __forceinline__ float tanhf_(float x){
  float ax = fabsf(x);
  float t = 1.f - 2.f/(__expf(2.f*ax)+1.f);   // stable, saturates to 1
  return copysignf(t, x);
}

// ---------------------------------------------------------------------------
// Kernel A: P_med[v][j] = sum_e med_table[v][e] * W_ih[j][64+e]
// (dec-input contribution to GRU pre-activations, per vocab entry; 134x192)
// ---------------------------------------------------------------------------
__global__ __launch_bounds__(256) void k_pmed(const float* __restrict__ mt,
    const float* __restrict__ wih, float* __restrict__ pmed){
  int o = blockIdx.x*256 + threadIdx.x;
  if (o >= 134*J3_) return;
  int v = o / J3_, j = o - v*J3_;
  const float* mr = mt + v*E_;
  const float* wr = wih + j*128 + E_;   // right half of W_ih row j
  float a = 0.f;
  #pragma unroll
  for (int k=0;k<E_;k++) a = fmaf(mr[k], wr[k], a);
  pmed[o] = a;
}

// ---------------------------------------------------------------------------
// Kernel B: per-row step-invariant attention context + gi_ctx.
// attn = softmax(d_score + d_mask) is h-independent (uniform shift), so
// ctx is constant over steps. gi_ctx[j] = ctx . W_ih_left[j] + b_ih[j].
// One wave per row; lane e holds element e; demb kept in 40 VGPRs.
// ---------------------------------------------------------------------------
__global__ __launch_bounds__(256) void k_ctx(const int* __restrict__ dis,
    const float* __restrict__ dmask, const float* __restrict__ dt,
    const float* __restrict__ aw, const float* __restrict__ wih,
    const float* __restrict__ bih, float* __restrict__ gictx){
  int lane = threadIdx.x & 63;
  int r = blockIdx.x*4 + (threadIdx.x>>6);
  float wd = aw[E_ + lane];                       // w_d = attn_w[0, 64:]
  float dreg[ND_], sc[ND_];
  const int*   drow = dis   + (size_t)r*ND_;
  const float* mrow = dmask + (size_t)r*ND_;
  #pragma unroll
  for (int n=0;n<ND_;n++){
    int idx = drow[n];                            // wave-uniform load
    float d = dt[(size_t)idx*E_ + lane];          // coalesced 256B row
    dreg[n] = d;
    float p = d*wd;
    #pragma unroll
    for (int m=1;m<64;m<<=1) p += __shfl_xor(p, m);   // full-wave sum
    sc[n] = p + mrow[n];                          // all lanes hold d_score[n]
  }
  float mx = sc[0];
  #pragma unroll
  for (int n=1;n<ND_;n++) mx = fmaxf(mx, sc[n]);
  float ss = 0.f;
  #pragma unroll
  for (int n=0;n<ND_;n++){ sc[n] = __expf(sc[n]-mx); ss += sc[n]; }
  float inv = 1.f/ss;
  float ctx = 0.f;
  #pragma unroll
  for (int n=0;n<ND_;n++) ctx = fmaf(sc[n], dreg[n], ctx);
  ctx *= inv;                                     // ctx[e] in lane e
  // gi_ctx: lane computes gate cols {e, e+64, e+128}
  float a0 = bih[lane], a1 = bih[lane+64], a2 = bih[lane+128];
  #pragma unroll
  for (int k=0;k<E_;k++){
    float xk = __shfl(ctx, k);
    a0 = fmaf(xk, wih[(lane      )*128 + k], a0);
    a1 = fmaf(xk, wih[(lane+ 64  )*128 + k], a1);
    a2 = fmaf(xk, wih[(lane+128  )*128 + k], a2);
  }
  float* g = gictx + (size_t)r*J3_;
  g[lane] = a0; g[lane+64] = a1; g[lane+128] = a2;
}

// ---------------------------------------------------------------------------
// Kernel C: main 31-step GRU + logits. 256 blocks x 512 threads.
// 32 rows/block, 8 waves, 4 rows/wave; wave-private h columns in LDS ->
// no barriers inside the step loop. Lane e owns gate/vocab cols
// {e, e+64, e+128}; GRU pointwise is register-only.
// ---------------------------------------------------------------------------
__global__ __launch_bounds__(512,2) void k_main(const int* __restrict__ meds,
    const float* __restrict__ whh, const float* __restrict__ bhh,
    const float* __restrict__ wo, const float* __restrict__ wob,
    const float* __restrict__ mt, const float* __restrict__ pmed,
    const float* __restrict__ gictx, float* __restrict__ out){
  __shared__ __align__(16) float sWhh[E_][J3_];   // W_hh^T  (k-major)  48K
  __shared__ __align__(16) float sWoT[E_][J3_];   // wo^T padded to 192 48K
  __shared__ __align__(16) float sGiC[RPB_][J3_]; // gi_ctx (incl b_ih) 24K
  __shared__ __align__(16) float sHT[E_][36];     // h^T, pad 36 for b128 9K
  __shared__ float sWob[J3_];
  __shared__ float sBhh[J3_];
  __shared__ int   sLM[RPB_][NSTEP_];             // last_med indices    4K
  int tid = threadIdx.x;
  int rowbase = blockIdx.x * RPB_;
  for (int i=tid;i<J3_*E_;i+=512){ int j=i>>6, k=i&63; sWhh[k][j] = whh[i]; }
  for (int i=tid;i<E_*J3_;i+=512){ int k=i/J3_, v=i-k*J3_;
      sWoT[k][v] = (v<VO_)? wo[v*E_+k] : 0.f; }
  for (int i=tid;i<J3_;i+=512){ sWob[i] = (i<VO_)? wob[i] : 0.f; sBhh[i] = bhh[i]; }
  for (int i=tid;i<RPB_*NSTEP_;i+=512){ int rr=i/NSTEP_, t=i-rr*NSTEP_;
      sLM[rr][t] = (t==0)? SOS_ : meds[(size_t)(rowbase+rr)*NM_ + (t-1)]; }
  for (int i=tid;i<RPB_*J3_;i+=512){ sGiC[i/J3_][i%J3_] = gictx[(size_t)rowbase*J3_ + i]; }
  for (int i=tid;i<E_*RPB_;i+=512){ int k=i>>5, rr=i&31; sHT[k][rr] = mt[SOS_*E_ + k]; }
  __syncthreads();

  int rg = tid>>6, e = tid&63;
  int r0 = rg*4;                                  // this wave's 4 rows
  float bhr = sBhh[e], bhz = sBhh[e+64], bhn = sBhh[e+128];
  float wb0 = sWob[e], wb1 = sWob[e+64], wb2 = sWob[e+128];
  bool has2 = (e < VO_-128);                      // e < 5

  for (int t=0;t<NSTEP_;t++){
    // ---- gh = h @ W_hh^T + b_hh (K=64) ----
    float gr[4], gz[4], gn[4];
    #pragma unroll
    for (int i=0;i<4;i++){ gr[i]=bhr; gz[i]=bhz; gn[i]=bhn; }
    #pragma unroll 16
    for (int k=0;k<E_;k++){
      float4 xv = *(const float4*)&sHT[k][r0];    // wave-uniform b128
      float w0 = sWhh[k][e], w1 = sWhh[k][e+64], w2 = sWhh[k][e+128];
      float x4[4] = {xv.x, xv.y, xv.z, xv.w};
      #pragma unroll
      for (int i=0;i<4;i++){
        gr[i] = fmaf(x4[i], w0, gr[i]);
        gz[i] = fmaf(x4[i], w1, gz[i]);
        gn[i] = fmaf(x4[i], w2, gn[i]);
      }
    }
    // ---- pointwise GRU (register-only; gi = gi_ctx + P_med[lm]) ----
    #pragma unroll
    for (int i=0;i<4;i++){
      int rr = r0+i;
      int lm = sLM[rr][t];                        // wave-uniform
      const float* pr = pmed + (size_t)lm*J3_;    // coalesced gather
      float ir  = sGiC[rr][e]     + pr[e]     + gr[i];
      float iz  = sGiC[rr][e+64]  + pr[e+64]  + gz[i];
      float in2 = sGiC[rr][e+128] + pr[e+128];
      float rr_ = sigmoidf_(ir);
      float zz  = sigmoidf_(iz);
      float nn  = tanhf_(in2 + rr_*gn[i]);        // gn holds h_n (+b_hh_n)
      float hp  = sHT[e][rr];
      float hv  = (1.f-zz)*nn + zz*hp;
      sHT[e][rr] = hv;                            // wave-private column
    }
    // ---- logits = h_new @ wo^T + wo_b (K=64) ----
    float L0[4], L1[4], L2[4];
    #pragma unroll
    for (int i=0;i<4;i++){ L0[i]=0.f; L1[i]=0.f; L2[i]=0.f; }
    #pragma unroll 16
    for (int k=0;k<E_;k++){
      float4 xv = *(const float4*)&sHT[k][r0];
      float w0 = sWoT[k][e], w1 = sWoT[k][e+64], w2 = sWoT[k][e+128];
      float x4[4] = {xv.x, xv.y, xv.z, xv.w};
      #pragma unroll
      for (int i=0;i<4;i++){
        L0[i] = fmaf(x4[i], w0, L0[i]);
        L1[i] = fmaf(x4[i], w1, L1[i]);
        L2[i] = fmaf(x4[i], w2, L2[i]);
      }
    }
    // ---- log_softmax over 133 (3 vals/lane, full-wave butterflies) ----
    #pragma unroll
    for (int i=0;i<4;i++){
      float l0 = L0[i]+wb0, l1 = L1[i]+wb1, l2v = L2[i]+wb2;
      float l2 = has2 ? l2v : -INFINITY;
      float m = fmaxf(fmaxf(l0,l1),l2);
      #pragma unroll
      for (int mm=1;mm<64;mm<<=1) m = fmaxf(m, __shfl_xor(m,mm));
      float s = __expf(l0-m) + __expf(l1-m) + (has2? __expf(l2-m) : 0.f);
      #pragma unroll
      for (int mm=1;mm<64;mm<<=1) s += __shfl_xor(s,mm);
      float lg = m + __logf(s);
      size_t ob = ((size_t)(rowbase+r0+i)*NSTEP_ + t)*VO_;
      out[ob+e]    = l0 - lg;
      out[ob+64+e] = l1 - lg;
      if (has2) out[ob+128+e] = l2v - lg;
    }
  }
}

extern "C" void kernel_launch(void* const* d_in, const int* in_sizes, int n_in,
                              void* d_out, int out_size, void* d_ws, size_t ws_size,
                              hipStream_t stream){
  const int*   dis  = (const int*)  d_in[0];
  // d_in[1] procedures, d_in[4] m_mask, d_in[5] seq_length: unused by reference
  const int*   meds = (const int*)  d_in[2];
  const float* dmask= (const float*)d_in[3];
  const float* dt   = (const float*)d_in[6];
  const float* mt   = (const float*)d_in[7];
  const float* aw   = (const float*)d_in[8];
  // d_in[9] attn_b: uniform shift, cancels in softmax
  const float* wih  = (const float*)d_in[10];
  const float* whh  = (const float*)d_in[11];
  const float* bih  = (const float*)d_in[12];
  const float* bhh  = (const float*)d_in[13];
  const float* wo   = (const float*)d_in[14];
  const float* wob  = (const float*)d_in[15];
  float* outp = (float*)d_out;
  float* ws   = (float*)d_ws;
  float* pmed  = ws;                 // 134*192 floats
  float* gictx = ws + 134*J3_;       // 8192*192 floats (~6.3 MB total ws use)

  k_pmed<<<(134*J3_+255)/256, 256, 0, stream>>>(mt, wih, pmed);
  k_ctx <<<NROW_/4,           256, 0, stream>>>(dis, dmask, dt, aw, wih, bih, gictx);
  k_main<<<NROW_/RPB_,        512, 0, stream>>>(meds, whh, bhh, wo, wob, mt, pmed, gictx, outp);
}

// Round 2
// 161.734 us; speedup vs baseline: 2.2076x; 2.2076x over previous
//
#include <hip/hip_runtime.h>
#include <math.h>

// Problem constants
#define E_     64     // embedding dim == wavefront size
#define ND_    40     // diseases per visit
#define NM_    30     // medications per visit
#define NSTEP_ 31     // NM+1 decode steps
#define VO_    133    // VM+2 output vocab
#define J3_    192    // 3*E (GRU gates)
#define NROW_  8192   // B*S
#define RPB_   32     // rows per block in main kernel
#define SOS_   131    // VM
#define NC_    388    // sC padded stride (floats); 388%32==4 -> 2-way max
#define NACT_  325    // real combined cols: 192 gh + 133 logits

typedef __attribute__((ext_vector_type(8))) short short8;
typedef __attribute__((ext_vector_type(4))) float f32x4;

__device__ __forceinline__ float sigmoidf_(float x){ return 1.f/(1.f+__expf(-x)); }
__device__ __forceinline__ float tanhf_(float x){
  float ax = fabsf(x);
  float t = 1.f - 2.f/(__expf(2.f*ax)+1.f);   // stable, saturates to 1
  return copysignf(t, x);
}
__device__ __forceinline__ unsigned short f2bf(float f){
  union { float f; unsigned u; } x; x.f = f;
  unsigned r = (x.u + 0x7fffu + ((x.u >> 16) & 1u)) >> 16;  // RNE
  return (unsigned short)r;
}

// ---------------------------------------------------------------------------
// Kernel A: P_med[v][j] = sum_e med_table[v][e] * W_ih[j][64+e]   (134x192)
// ---------------------------------------------------------------------------
__global__ __launch_bounds__(256) void k_pmed(const float* __restrict__ mt,
    const float* __restrict__ wih, float* __restrict__ pmed){
  int o = blockIdx.x*256 + threadIdx.x;
  if (o >= 134*J3_) return;
  int v = o / J3_, j = o - v*J3_;
  const float* mr = mt + v*E_;
  const float* wr = wih + j*128 + E_;
  float a = 0.f;
  #pragma unroll
  for (int k=0;k<E_;k++) a = fmaf(mr[k], wr[k], a);
  pmed[o] = a;
}

// ---------------------------------------------------------------------------
// Kernel B: step-invariant attention context + gi_ctx (incl b_ih).
// attn = softmax(d_score + d_mask) is h-independent (uniform shift).
// ---------------------------------------------------------------------------
__global__ __launch_bounds__(256) void k_ctx(const int* __restrict__ dis,
    const float* __restrict__ dmask, const float* __restrict__ dt,
    const float* __restrict__ aw, const float* __restrict__ wih,
    const float* __restrict__ bih, float* __restrict__ gictx){
  int lane = threadIdx.x & 63;
  int r = blockIdx.x*4 + (threadIdx.x>>6);
  float wd = aw[E_ + lane];
  float dreg[ND_], sc[ND_];
  const int*   drow = dis   + (size_t)r*ND_;
  const float* mrow = dmask + (size_t)r*ND_;
  #pragma unroll
  for (int n=0;n<ND_;n++){
    int idx = drow[n];
    float d = dt[(size_t)idx*E_ + lane];
    dreg[n] = d;
    float p = d*wd;
    #pragma unroll
    for (int m=1;m<64;m<<=1) p += __shfl_xor(p, m);
    sc[n] = p + mrow[n];
  }
  float mx = sc[0];
  #pragma unroll
  for (int n=1;n<ND_;n++) mx = fmaxf(mx, sc[n]);
  float ss = 0.f;
  #pragma unroll
  for (int n=0;n<ND_;n++){ sc[n] = __expf(sc[n]-mx); ss += sc[n]; }
  float inv = 1.f/ss;
  float ctx = 0.f;
  #pragma unroll
  for (int n=0;n<ND_;n++) ctx = fmaf(sc[n], dreg[n], ctx);
  ctx *= inv;
  float a0 = bih[lane], a1 = bih[lane+64], a2 = bih[lane+128];
  #pragma unroll
  for (int k=0;k<E_;k++){
    float xk = __shfl(ctx, k);
    a0 = fmaf(xk, wih[(lane      )*128 + k], a0);
    a1 = fmaf(xk, wih[(lane+ 64  )*128 + k], a1);
    a2 = fmaf(xk, wih[(lane+128  )*128 + k], a2);
  }
  float* g = gictx + (size_t)r*J3_;
  g[lane] = a0; g[lane+64] = a1; g[lane+128] = a2;
}

// ---------------------------------------------------------------------------
// Kernel C: fused MFMA GRU decoder.
// 256 blocks x 1024 threads (16 waves). 32 rows/block, 2 rows/wave pointwise.
// Per step: ONE combined GEMM  h_t(32x64) x [W_hh^T | wo^T](64x384) via
// 16x16x32 bf16 MFMA; N-tiles split across waves; weights = loop-invariant
// register B-fragments. h round-trips via XOR-swizzled bf16 LDS; C via
// pad-388 fp32 LDS. Logits of step t-1 come from the wo-half at iter t.
// ---------------------------------------------------------------------------
__global__ __launch_bounds__(1024) void k_main(const int* __restrict__ meds,
    const float* __restrict__ whh, const float* __restrict__ bhh,
    const float* __restrict__ wo, const float* __restrict__ wob,
    const float* __restrict__ mt, const float* __restrict__ pmed,
    const float* __restrict__ gictx, float* __restrict__ out)
{
  __shared__ __align__(16) unsigned short hA[RPB_*E_];  // 4KB swizzled bf16 h
  __shared__ __align__(16) float sC[RPB_*NC_];          // 48.5KB GEMM out
  __shared__ int sLM[RPB_*32];                          // 4KB last-med idx

  const int tid = threadIdx.x;
  const int w = tid >> 6, l = tid & 63;
  const int l15 = l & 15, l4 = l >> 4;
  const int rowbase = blockIdx.x * RPB_;

  for (int i = tid; i < RPB_*NSTEP_; i += 1024){
    int rr = i / NSTEP_, t = i - rr*NSTEP_;
    sLM[rr*32 + t] = (t==0) ? SOS_ : meds[(size_t)(rowbase+rr)*NM_ + (t-1)];
  }

  // ---- loop-invariant weight B-fragments in registers ----
  // wave w<8 owns ntiles {2w, 2w+1}; wave w>=8 owns ntile {8+w}.
  // Combined cols: c<192 -> whh[c][k]; c-192<133 -> wo[c-192][k]; else 0.
  const int n0 = (w < 8) ? 2*w : (8 + w);
  const int n1 = (w < 8) ? (2*w + 1) : -1;
  const bool act0 = (n0*16 < NACT_);
  const bool act1 = (n1 >= 0) && (n1*16 < NACT_);
  short8 B00 = {0,0,0,0,0,0,0,0}, B01 = B00, B10 = B00, B11 = B00;

  #define LOADB_(Bk0, Bk1, n) do {                                   \
    int c_ = (n)*16 + l15;                                           \
    _Pragma("unroll")                                                \
    for (int ks_ = 0; ks_ < 2; ++ks_) {                              \
      int k0_ = ks_*32 + l4*8;                                       \
      float v_[8];                                                   \
      if (c_ < J3_) {                                                \
        const float* s_ = whh + (size_t)c_*E_ + k0_;                 \
        _Pragma("unroll") for (int j_=0;j_<8;j_++) v_[j_] = s_[j_];  \
      } else if (c_ < 192+VO_) {                                     \
        const float* s_ = wo + (size_t)(c_-192)*E_ + k0_;            \
        _Pragma("unroll") for (int j_=0;j_<8;j_++) v_[j_] = s_[j_];  \
      } else {                                                       \
        _Pragma("unroll") for (int j_=0;j_<8;j_++) v_[j_] = 0.f;     \
      }                                                              \
      short8 f_;                                                     \
      _Pragma("unroll") for (int j_=0;j_<8;j_++) f_[j_] = (short)f2bf(v_[j_]); \
      if (ks_==0) Bk0 = f_; else Bk1 = f_;                           \
    } } while(0)

  if (act0) LOADB_(B00, B01, n0);
  if (act1) LOADB_(B10, B11, n1);

  // ---- per-thread loop-invariant state (rows 2w, 2w+1; gate col l) ----
  const int r0 = 2*w, r1 = 2*w + 1;
  const float* g0p = gictx + (size_t)(rowbase + r0)*J3_;
  const float* g1p = gictx + (size_t)(rowbase + r1)*J3_;
  float gi00=g0p[l], gi01=g0p[l+64], gi02=g0p[l+128];
  float gi10=g1p[l], gi11=g1p[l+64], gi12=g1p[l+128];
  float bhr=bhh[l], bhz=bhh[l+64], bhn=bhh[l+128];
  const bool has2 = (l < 5);
  float wb0=wob[l], wb1=wob[l+64], wb2 = has2 ? wob[l+128] : 0.f;

  // ---- init h0 = med_table[SOS] (same for all rows) ----
  float h0v = mt[SOS_*E_ + l];
  float hr0 = h0v, hr1 = h0v;
  hA[r0*E_ + (((l>>3) ^ (r0 & 7))<<3) + (l&7)] = f2bf(hr0);
  hA[r1*E_ + (((l>>3) ^ (r1 & 7))<<3) + (l&7)] = f2bf(hr1);
  __syncthreads();

  for (int t = 0; t < NSTEP_+1; ++t) {
    // ---- A fragments (all 32 rows, both K halves) from swizzled hA ----
    const int ra = l15, rb = 16 + l15;
    short8 A00 = *(const short8*)&hA[ra*E_ + (((l4  ) ^ (ra & 7))<<3)];
    short8 A01 = *(const short8*)&hA[ra*E_ + (((l4+4) ^ (ra & 7))<<3)];
    short8 A10 = *(const short8*)&hA[rb*E_ + (((l4  ) ^ (rb & 7))<<3)];
    short8 A11 = *(const short8*)&hA[rb*E_ + (((l4+4) ^ (rb & 7))<<3)];
    if (act0) {
      f32x4 c00 = {0.f,0.f,0.f,0.f}, c01 = {0.f,0.f,0.f,0.f};
      c00 = __builtin_amdgcn_mfma_f32_16x16x32_bf16(A00, B00, c00, 0,0,0);
      c00 = __builtin_amdgcn_mfma_f32_16x16x32_bf16(A01, B01, c00, 0,0,0);
      c01 = __builtin_amdgcn_mfma_f32_16x16x32_bf16(A10, B00, c01, 0,0,0);
      c01 = __builtin_amdgcn_mfma_f32_16x16x32_bf16(A11, B01, c01, 0,0,0);
      int cb = n0*16 + l15, rw = l4*4;
      #pragma unroll
      for (int i=0;i<4;i++) sC[(rw+i)*NC_ + cb]    = c00[i];
      #pragma unroll
      for (int i=0;i<4;i++) sC[(16+rw+i)*NC_ + cb] = c01[i];
    }
    if (act1) {
      f32x4 c10 = {0.f,0.f,0.f,0.f}, c11 = {0.f,0.f,0.f,0.f};
      c10 = __builtin_amdgcn_mfma_f32_16x16x32_bf16(A00, B10, c10, 0,0,0);
      c10 = __builtin_amdgcn_mfma_f32_16x16x32_bf16(A01, B11, c10, 0,0,0);
      c11 = __builtin_amdgcn_mfma_f32_16x16x32_bf16(A10, B10, c11, 0,0,0);
      c11 = __builtin_amdgcn_mfma_f32_16x16x32_bf16(A11, B11, c11, 0,0,0);
      int cb = n1*16 + l15, rw = l4*4;
      #pragma unroll
      for (int i=0;i<4;i++) sC[(rw+i)*NC_ + cb]    = c10[i];
      #pragma unroll
      for (int i=0;i<4;i++) sC[(16+rw+i)*NC_ + cb] = c11[i];
    }
    __syncthreads();

    if (t < NSTEP_) {
      // ---- pointwise GRU for rows r0, r1 (gh = sC cols 0..191) ----
      int lm0 = sLM[r0*32 + t], lm1 = sLM[r1*32 + t];
      const float* p0 = pmed + (size_t)lm0*J3_;
      const float* p1 = pmed + (size_t)lm1*J3_;
      {
        float i_r = gi00 + p0[l]     + sC[r0*NC_ + l]    + bhr;
        float i_z = gi01 + p0[l+64]  + sC[r0*NC_ + l+64] + bhz;
        float i_n = gi02 + p0[l+128];
        float hnn = sC[r0*NC_ + l+128] + bhn;
        float rg = sigmoidf_(i_r), zg = sigmoidf_(i_z);
        float ng = tanhf_(i_n + rg*hnn);
        hr0 = (1.f-zg)*ng + zg*hr0;
        hA[r0*E_ + (((l>>3) ^ (r0 & 7))<<3) + (l&7)] = f2bf(hr0);
      }
      {
        float i_r = gi10 + p1[l]     + sC[r1*NC_ + l]    + bhr;
        float i_z = gi11 + p1[l+64]  + sC[r1*NC_ + l+64] + bhz;
        float i_n = gi12 + p1[l+128];
        float hnn = sC[r1*NC_ + l+128] + bhn;
        float rg = sigmoidf_(i_r), zg = sigmoidf_(i_z);
        float ng = tanhf_(i_n + rg*hnn);
        hr1 = (1.f-zg)*ng + zg*hr1;
        hA[r1*E_ + (((l>>3) ^ (r1 & 7))<<3) + (l&7)] = f2bf(hr1);
      }
    }
    if (t >= 1) {
      // ---- log_softmax + store for step t-1 (logits = sC cols 192..324) ----
      {
        float l0  = sC[r0*NC_ + 192 + l] + wb0;
        float l1  = sC[r0*NC_ + 256 + l] + wb1;
        float l2v = sC[r0*NC_ + 320 + l] + wb2;
        float l2 = has2 ? l2v : -INFINITY;
        float m = fmaxf(fmaxf(l0,l1),l2);
        #pragma unroll
        for (int mm=1;mm<64;mm<<=1) m = fmaxf(m, __shfl_xor(m,mm));
        float s = __expf(l0-m) + __expf(l1-m) + (has2? __expf(l2-m) : 0.f);
        #pragma unroll
        for (int mm=1;mm<64;mm<<=1) s += __shfl_xor(s,mm);
        float lg = m + __logf(s);
        size_t ob = ((size_t)(rowbase+r0)*NSTEP_ + (t-1))*VO_;
        out[ob + l] = l0 - lg;
        out[ob + 64 + l] = l1 - lg;
        if (has2) out[ob + 128 + l] = l2v - lg;
      }
      {
        float l0  = sC[r1*NC_ + 192 + l] + wb0;
        float l1  = sC[r1*NC_ + 256 + l] + wb1;
        float l2v = sC[r1*NC_ + 320 + l] + wb2;
        float l2 = has2 ? l2v : -INFINITY;
        float m = fmaxf(fmaxf(l0,l1),l2);
        #pragma unroll
        for (int mm=1;mm<64;mm<<=1) m = fmaxf(m, __shfl_xor(m,mm));
        float s = __expf(l0-m) + __expf(l1-m) + (has2? __expf(l2-m) : 0.f);
        #pragma unroll
        for (int mm=1;mm<64;mm<<=1) s += __shfl_xor(s,mm);
        float lg = m + __logf(s);
        size_t ob = ((size_t)(rowbase+r1)*NSTEP_ + (t-1))*VO_;
        out[ob + l] = l0 - lg;
        out[ob + 64 + l] = l1 - lg;
        if (has2) out[ob + 128 + l] = l2v - lg;
      }
    }
    __syncthreads();
  }
}

extern "C" void kernel_launch(void* const* d_in, const int* in_sizes, int n_in,
                              void* d_out, int out_size, void* d_ws, size_t ws_size,
                              hipStream_t stream){
  const int*   dis  = (const int*)  d_in[0];
  const int*   meds = (const int*)  d_in[2];
  const float* dmask= (const float*)d_in[3];
  const float* dt   = (const float*)d_in[6];
  const float* mt   = (const float*)d_in[7];
  const float* aw   = (const float*)d_in[8];
  const float* wih  = (const float*)d_in[10];
  const float* whh  = (const float*)d_in[11];
  const float* bih  = (const float*)d_in[12];
  const float* bhh  = (const float*)d_in[13];
  const float* wo   = (const float*)d_in[14];
  const float* wob  = (const float*)d_in[15];
  float* outp = (float*)d_out;
  float* ws   = (float*)d_ws;
  float* pmed  = ws;                 // 134*192 floats
  float* gictx = ws + 134*J3_;       // 8192*192 floats

  k_pmed<<<(134*J3_+255)/256, 256, 0, stream>>>(mt, wih, pmed);
  k_ctx <<<NROW_/4,           256, 0, stream>>>(dis, dmask, dt, aw, wih, bih, gictx);
  k_main<<<NROW_/RPB_,       1024, 0, stream>>>(meds, whh, bhh, wo, wob, mt, pmed, gictx, outp);
}

// Round 3
// 140.185 us; speedup vs baseline: 2.5469x; 1.1537x over previous
//
#include <hip/hip_runtime.h>
#include <math.h>

// Problem constants
#define E_     64     // embedding dim == wavefront size
#define ND_    40     // diseases per visit
#define NM_    30     // medications per visit
#define NSTEP_ 31     // NM+1 decode steps
#define VO_    133    // VM+2 output vocab
#define J3_    192    // 3*E (GRU gates)
#define NROW_  8192   // B*S
#define RPB_   8      // rows per block in main kernel
#define SOS_   131    // VM
#define NC_    388    // sC padded stride (floats); 388%32==4 -> 2-way max
#define NACT_  325    // real combined cols: 192 gh + 133 logits

typedef __attribute__((ext_vector_type(8))) short short8;
typedef __attribute__((ext_vector_type(4))) float f32x4;

__device__ __forceinline__ float sigmoidf_(float x){ return 1.f/(1.f+__expf(-x)); }
__device__ __forceinline__ float tanhf_(float x){
  float ax = fabsf(x);
  float t = 1.f - 2.f/(__expf(2.f*ax)+1.f);   // stable, saturates to 1
  return copysignf(t, x);
}
__device__ __forceinline__ unsigned short f2bf(float f){
  union { float f; unsigned u; } x; x.f = f;
  unsigned r = (x.u + 0x7fffu + ((x.u >> 16) & 1u)) >> 16;  // RNE
  return (unsigned short)r;
}

// ---------------------------------------------------------------------------
// Kernel A: P_med[v][j] = sum_e med_table[v][e] * W_ih[j][64+e]   (134x192)
// ---------------------------------------------------------------------------
__global__ __launch_bounds__(256) void k_pmed(const float* __restrict__ mt,
    const float* __restrict__ wih, float* __restrict__ pmed){
  int o = blockIdx.x*256 + threadIdx.x;
  if (o >= 134*J3_) return;
  int v = o / J3_, j = o - v*J3_;
  const float* mr = mt + v*E_;
  const float* wr = wih + j*128 + E_;
  float a = 0.f;
  #pragma unroll
  for (int k=0;k<E_;k++) a = fmaf(mr[k], wr[k], a);
  pmed[o] = a;
}

// ---------------------------------------------------------------------------
// Kernel B: step-invariant attention context (bf16 out).
// attn = softmax(d_score + d_mask) is h-independent (uniform shift).
// One wave per row; lane e holds element e.
// ---------------------------------------------------------------------------
__global__ __launch_bounds__(256) void k_ctx(const int* __restrict__ dis,
    const float* __restrict__ dmask, const float* __restrict__ dt,
    const float* __restrict__ aw, unsigned short* __restrict__ ctxb){
  int lane = threadIdx.x & 63;
  int r = blockIdx.x*4 + (threadIdx.x>>6);
  float wd = aw[E_ + lane];
  float dreg[ND_], sc[ND_];
  const int*   drow = dis   + (size_t)r*ND_;
  const float* mrow = dmask + (size_t)r*ND_;
  #pragma unroll
  for (int n=0;n<ND_;n++){
    int idx = drow[n];
    float d = dt[(size_t)idx*E_ + lane];
    dreg[n] = d;
    float p = d*wd;
    #pragma unroll
    for (int m=1;m<64;m<<=1) p += __shfl_xor(p, m);
    sc[n] = p + mrow[n];
  }
  float mx = sc[0];
  #pragma unroll
  for (int n=1;n<ND_;n++) mx = fmaxf(mx, sc[n]);
  float ss = 0.f;
  #pragma unroll
  for (int n=0;n<ND_;n++){ sc[n] = __expf(sc[n]-mx); ss += sc[n]; }
  float inv = 1.f/ss;
  float ctx = 0.f;
  #pragma unroll
  for (int n=0;n<ND_;n++) ctx = fmaf(sc[n], dreg[n], ctx);
  ctx *= inv;
  ctxb[(size_t)r*E_ + lane] = f2bf(ctx);
}

// ---------------------------------------------------------------------------
// Kernel B2: gi_ctx = ctx @ W_ih_left^T + b_ih   (8192x192, K=64) via MFMA.
// 256 blocks x 256 threads, 32 rows/block, 4 waves x 3 n-tiles.
// ---------------------------------------------------------------------------
__global__ __launch_bounds__(256) void k_gi(const unsigned short* __restrict__ ctxb,
    const float* __restrict__ wih, const float* __restrict__ bih,
    float* __restrict__ gictx){
  __shared__ __align__(16) unsigned short sA[32*E_];   // 4KB swizzled bf16 ctx
  const int tid = threadIdx.x;
  const int w = tid >> 6, l = tid & 63, l15 = l & 15, l4 = l >> 4;
  const int rowbase = blockIdx.x * 32;
  for (int i = tid; i < 32*E_; i += 256){
    int r = i >> 6, k = i & 63;
    sA[r*E_ + (((k>>3) ^ (r&7))<<3) + (k&7)] = ctxb[(size_t)rowbase*E_ + i];
  }
  __syncthreads();
  // B fragments: tiles n = w, w+4, w+8  (12 tiles cover 192 cols)
  short8 Bk0[3], Bk1[3];
  #pragma unroll
  for (int j = 0; j < 3; j++){
    int c = (w + 4*j)*16 + l15;
    const float* s0 = wih + (size_t)c*128 + l4*8;        // K-half 0
    const float* s1 = s0 + 32;                           // K-half 1
    short8 f0, f1;
    #pragma unroll
    for (int jj = 0; jj < 8; jj++){ f0[jj] = (short)f2bf(s0[jj]); f1[jj] = (short)f2bf(s1[jj]); }
    Bk0[j] = f0; Bk1[j] = f1;
  }
  const int ra = l15, rb = 16 + l15;
  short8 A00 = *(const short8*)&sA[ra*E_ + (((l4  ) ^ (ra&7))<<3)];
  short8 A01 = *(const short8*)&sA[ra*E_ + (((l4+4) ^ (ra&7))<<3)];
  short8 A10 = *(const short8*)&sA[rb*E_ + (((l4  ) ^ (rb&7))<<3)];
  short8 A11 = *(const short8*)&sA[rb*E_ + (((l4+4) ^ (rb&7))<<3)];
  #pragma unroll
  for (int j = 0; j < 3; j++){
    int cb = (w + 4*j)*16 + l15;
    float bv = bih[cb];
    f32x4 c0 = {0.f,0.f,0.f,0.f}, c1 = {0.f,0.f,0.f,0.f};
    c0 = __builtin_amdgcn_mfma_f32_16x16x32_bf16(A00, Bk0[j], c0, 0,0,0);
    c0 = __builtin_amdgcn_mfma_f32_16x16x32_bf16(A01, Bk1[j], c0, 0,0,0);
    c1 = __builtin_amdgcn_mfma_f32_16x16x32_bf16(A10, Bk0[j], c1, 0,0,0);
    c1 = __builtin_amdgcn_mfma_f32_16x16x32_bf16(A11, Bk1[j], c1, 0,0,0);
    #pragma unroll
    for (int i = 0; i < 4; i++){
      gictx[(size_t)(rowbase + l4*4 + i)*J3_ + cb]      = c0[i] + bv;
      gictx[(size_t)(rowbase + 16 + l4*4 + i)*J3_ + cb] = c1[i] + bv;
    }
  }
}

// ---------------------------------------------------------------------------
// Kernel C: fused MFMA GRU decoder.
// 1024 blocks x 256 threads (4 waves). 8 rows/block -> 4 independent
// barrier domains per CU (latency hiding across blocks). M-tile = 16 with
// rows 8..15 zeroed. 21 active n-tiles, 6 per wave as register B-frags.
// ---------------------------------------------------------------------------
__global__ __launch_bounds__(256,4) void k_main(const int* __restrict__ meds,
    const float* __restrict__ whh, const float* __restrict__ bhh,
    const float* __restrict__ wo, const float* __restrict__ wob,
    const float* __restrict__ mt, const float* __restrict__ pmed,
    const float* __restrict__ gictx, float* __restrict__ out)
{
  __shared__ __align__(16) unsigned short hA[16*E_];    // 2KB swizzled bf16 h
  __shared__ __align__(16) float sC[RPB_*NC_];          // 12.4KB GEMM out
  __shared__ int sLM[RPB_*32];                          // 1KB last-med idx

  const int tid = threadIdx.x;
  const int w = tid >> 6, l = tid & 63;
  const int l15 = l & 15, l4 = l >> 4;
  const int rowbase = blockIdx.x * RPB_;

  for (int i = tid; i < RPB_*NSTEP_; i += 256){
    int rr = i / NSTEP_, t = i - rr*NSTEP_;
    sLM[rr*32 + t] = (t==0) ? SOS_ : meds[(size_t)(rowbase+rr)*NM_ + (t-1)];
  }
  // init hA: rows 0..7 = h0 = med_table[SOS], rows 8..15 = 0
  for (int i = tid; i < 16*E_; i += 256){
    int r = i >> 6, k = i & 63;
    unsigned short v = (r < RPB_) ? f2bf(mt[SOS_*E_ + k]) : (unsigned short)0;
    hA[r*E_ + (((k>>3) ^ (r&7))<<3) + (k&7)] = v;
  }

  // ---- loop-invariant weight B-fragments: wave w owns tiles {w+4j} ----
  short8 B0[6], B1[6];
  bool act[6];
  #pragma unroll
  for (int j = 0; j < 6; j++){
    int n = w + 4*j;
    act[j] = (n*16 < NACT_);
    short8 z = {0,0,0,0,0,0,0,0};
    B0[j] = z; B1[j] = z;
    if (act[j]){
      int c = n*16 + l15;
      #pragma unroll
      for (int ks = 0; ks < 2; ks++){
        int k0 = ks*32 + l4*8;
        float v[8];
        if (c < J3_){
          const float* s = whh + (size_t)c*E_ + k0;
          #pragma unroll
          for (int jj=0;jj<8;jj++) v[jj] = s[jj];
        } else if (c < 192+VO_){
          const float* s = wo + (size_t)(c-192)*E_ + k0;
          #pragma unroll
          for (int jj=0;jj<8;jj++) v[jj] = s[jj];
        } else {
          #pragma unroll
          for (int jj=0;jj<8;jj++) v[jj] = 0.f;
        }
        short8 f;
        #pragma unroll
        for (int jj=0;jj<8;jj++) f[jj] = (short)f2bf(v[jj]);
        if (ks==0) B0[j] = f; else B1[j] = f;
      }
    }
  }

  // ---- per-thread loop-invariant state: rows 2w, 2w+1; gate col l ----
  const int r0 = 2*w, r1 = 2*w + 1;
  const float* g0p = gictx + (size_t)(rowbase + r0)*J3_;
  const float* g1p = gictx + (size_t)(rowbase + r1)*J3_;
  float gi00=g0p[l], gi01=g0p[l+64], gi02=g0p[l+128];
  float gi10=g1p[l], gi11=g1p[l+64], gi12=g1p[l+128];
  float bhr=bhh[l], bhz=bhh[l+64], bhn=bhh[l+128];
  const bool has2 = (l < 5);
  float wb0=wob[l], wb1=wob[l+64], wb2 = has2 ? wob[l+128] : 0.f;

  float h0v = mt[SOS_*E_ + l];
  float hr0 = h0v, hr1 = h0v;
  __syncthreads();

  for (int t = 0; t < NSTEP_+1; ++t) {
    // ---- A fragments (M-tile 0: rows 0..15) from swizzled hA ----
    const int ra = l15;
    short8 A00 = *(const short8*)&hA[ra*E_ + (((l4  ) ^ (ra & 7))<<3)];
    short8 A01 = *(const short8*)&hA[ra*E_ + (((l4+4) ^ (ra & 7))<<3)];
    #pragma unroll
    for (int j = 0; j < 6; j++){
      if (act[j]){
        f32x4 c = {0.f,0.f,0.f,0.f};
        c = __builtin_amdgcn_mfma_f32_16x16x32_bf16(A00, B0[j], c, 0,0,0);
        c = __builtin_amdgcn_mfma_f32_16x16x32_bf16(A01, B1[j], c, 0,0,0);
        int cb = (w + 4*j)*16 + l15;
        if (l4 < 2){                       // only rows 0..7 are real
          #pragma unroll
          for (int i=0;i<4;i++) sC[(l4*4+i)*NC_ + cb] = c[i];
        }
      }
    }
    __syncthreads();

    if (t < NSTEP_) {
      // ---- pointwise GRU for rows r0, r1 (gh = sC cols 0..191) ----
      int lm0 = sLM[r0*32 + t], lm1 = sLM[r1*32 + t];
      const float* p0 = pmed + (size_t)lm0*J3_;
      const float* p1 = pmed + (size_t)lm1*J3_;
      {
        float i_r = gi00 + p0[l]     + sC[r0*NC_ + l]    + bhr;
        float i_z = gi01 + p0[l+64]  + sC[r0*NC_ + l+64] + bhz;
        float i_n = gi02 + p0[l+128];
        float hnn = sC[r0*NC_ + l+128] + bhn;
        float rg = sigmoidf_(i_r), zg = sigmoidf_(i_z);
        float ng = tanhf_(i_n + rg*hnn);
        hr0 = (1.f-zg)*ng + zg*hr0;
        hA[r0*E_ + (((l>>3) ^ (r0 & 7))<<3) + (l&7)] = f2bf(hr0);
      }
      {
        float i_r = gi10 + p1[l]     + sC[r1*NC_ + l]    + bhr;
        float i_z = gi11 + p1[l+64]  + sC[r1*NC_ + l+64] + bhz;
        float i_n = gi12 + p1[l+128];
        float hnn = sC[r1*NC_ + l+128] + bhn;
        float rg = sigmoidf_(i_r), zg = sigmoidf_(i_z);
        float ng = tanhf_(i_n + rg*hnn);
        hr1 = (1.f-zg)*ng + zg*hr1;
        hA[r1*E_ + (((l>>3) ^ (r1 & 7))<<3) + (l&7)] = f2bf(hr1);
      }
    }
    if (t >= 1) {
      // ---- log_softmax + store for step t-1 (logits = sC cols 192..324) ----
      {
        float l0  = sC[r0*NC_ + 192 + l] + wb0;
        float l1  = sC[r0*NC_ + 256 + l] + wb1;
        float l2v = sC[r0*NC_ + 320 + l] + wb2;
        float l2 = has2 ? l2v : -INFINITY;
        float m = fmaxf(fmaxf(l0,l1),l2);
        #pragma unroll
        for (int mm=1;mm<64;mm<<=1) m = fmaxf(m, __shfl_xor(m,mm));
        float s = __expf(l0-m) + __expf(l1-m) + (has2? __expf(l2-m) : 0.f);
        #pragma unroll
        for (int mm=1;mm<64;mm<<=1) s += __shfl_xor(s,mm);
        float lg = m + __logf(s);
        size_t ob = ((size_t)(rowbase+r0)*NSTEP_ + (t-1))*VO_;
        out[ob + l] = l0 - lg;
        out[ob + 64 + l] = l1 - lg;
        if (has2) out[ob + 128 + l] = l2v - lg;
      }
      {
        float l0  = sC[r1*NC_ + 192 + l] + wb0;
        float l1  = sC[r1*NC_ + 256 + l] + wb1;
        float l2v = sC[r1*NC_ + 320 + l] + wb2;
        float l2 = has2 ? l2v : -INFINITY;
        float m = fmaxf(fmaxf(l0,l1),l2);
        #pragma unroll
        for (int mm=1;mm<64;mm<<=1) m = fmaxf(m, __shfl_xor(m,mm));
        float s = __expf(l0-m) + __expf(l1-m) + (has2? __expf(l2-m) : 0.f);
        #pragma unroll
        for (int mm=1;mm<64;mm<<=1) s += __shfl_xor(s,mm);
        float lg = m + __logf(s);
        size_t ob = ((size_t)(rowbase+r1)*NSTEP_ + (t-1))*VO_;
        out[ob + l] = l0 - lg;
        out[ob + 64 + l] = l1 - lg;
        if (has2) out[ob + 128 + l] = l2v - lg;
      }
    }
    __syncthreads();
  }
}

extern "C" void kernel_launch(void* const* d_in, const int* in_sizes, int n_in,
                              void* d_out, int out_size, void* d_ws, size_t ws_size,
                              hipStream_t stream){
  const int*   dis  = (const int*)  d_in[0];
  const int*   meds = (const int*)  d_in[2];
  const float* dmask= (const float*)d_in[3];
  const float* dt   = (const float*)d_in[6];
  const float* mt   = (const float*)d_in[7];
  const float* aw   = (const float*)d_in[8];
  const float* wih  = (const float*)d_in[10];
  const float* whh  = (const float*)d_in[11];
  const float* bih  = (const float*)d_in[12];
  const float* bhh  = (const float*)d_in[13];
  const float* wo   = (const float*)d_in[14];
  const float* wob  = (const float*)d_in[15];
  float* outp = (float*)d_out;
  float* ws   = (float*)d_ws;
  float* pmed  = ws;                              // 134*192 f32
  float* gictx = ws + 134*J3_;                    // 8192*192 f32
  unsigned short* ctxb = (unsigned short*)(ws + 134*J3_ + (size_t)NROW_*J3_); // 8192*64 bf16

  k_pmed<<<(134*J3_+255)/256, 256, 0, stream>>>(mt, wih, pmed);
  k_ctx <<<NROW_/4,           256, 0, stream>>>(dis, dmask, dt, aw, ctxb);
  k_gi  <<<NROW_/32,          256, 0, stream>>>(ctxb, wih, bih, gictx);
  k_main<<<NROW_/RPB_,        256, 0, stream>>>(meds, whh, bhh, wo, wob, mt, pmed, gictx, outp);
}

// Round 4
// 129.217 us; speedup vs baseline: 2.7631x; 1.0849x over previous
//
#include <hip/hip_runtime.h>
#include <math.h>

// Problem constants
#define E_     64     // embedding dim == wavefront size
#define ND_    40     // diseases per visit
#define NM_    30     // medications per visit
#define NSTEP_ 31     // NM+1 decode steps
#define VO_    133    // VM+2 output vocab
#define J3_    192    // 3*E (GRU gates)
#define NROW_  8192   // B*S
#define RPB_   8      // rows per block in main kernel
#define SOS_   131    // VM
#define NC_    388    // sC padded stride (floats); 2-way max conflicts
#define NACT_  325    // combined cols: 192 gh + 133 logits

typedef __attribute__((ext_vector_type(8))) short short8;
typedef __attribute__((ext_vector_type(4))) float f32x4;

__device__ __forceinline__ float sigmoidf_(float x){ return 1.f/(1.f+__expf(-x)); }
__device__ __forceinline__ float tanhf_(float x){
  float ax = fabsf(x);
  float t = 1.f - 2.f/(__expf(2.f*ax)+1.f);   // stable, saturates to 1
  return copysignf(t, x);
}
__device__ __forceinline__ unsigned short f2bf(float f){
  union { float f; unsigned u; } x; x.f = f;
  unsigned r = (x.u + 0x7fffu + ((x.u >> 16) & 1u)) >> 16;  // RNE
  return (unsigned short)r;
}

// ---------------------------------------------------------------------------
// Kernel A: P_med[v][j] = sum_e med_table[v][e] * W_ih[j][64+e]   (134x192)
// ---------------------------------------------------------------------------
__global__ __launch_bounds__(256) void k_pmed(const float* __restrict__ mt,
    const float* __restrict__ wih, float* __restrict__ pmed){
  int o = blockIdx.x*256 + threadIdx.x;
  if (o >= 134*J3_) return;
  int v = o / J3_, j = o - v*J3_;
  const float* mr = mt + v*E_;
  const float* wr = wih + j*128 + E_;
  float a = 0.f;
  #pragma unroll
  for (int k=0;k<E_;k++) a = fmaf(mr[k], wr[k], a);
  pmed[o] = a;
}

// ---------------------------------------------------------------------------
// Kernel B: fully fused decoder. 1024 blocks x 512 threads (8 waves),
// 8 rows/block, 1 row/wave, 4 blocks/CU -> 32 waves/CU (max occupancy).
// Prologue: step-invariant attention ctx (2-pass, scores in LDS) +
// gi = ctx @ W_ih_left^T + b_ih (+b_hh fold for r,z) via MFMA.
// Main loop: per step one combined GEMM h(8x64) x [W_hh^T|wo^T](64x325)
// (M-tile 16, rows 8..15 zero); weights as loop-invariant register
// B-fragments (3 n-tiles/wave); pointwise GRU + max-free log_softmax
// (logits provably bounded -> exp cannot overflow fp32).
// ---------------------------------------------------------------------------
__global__ __launch_bounds__(512,8) void k_main(
    const int* __restrict__ dis, const float* __restrict__ dmask,
    const float* __restrict__ dt, const float* __restrict__ aw,
    const int* __restrict__ meds,
    const float* __restrict__ whh, const float* __restrict__ bhh,
    const float* __restrict__ wih, const float* __restrict__ bih,
    const float* __restrict__ wo, const float* __restrict__ wob,
    const float* __restrict__ mt, const float* __restrict__ pmed,
    float* __restrict__ out)
{
  __shared__ __align__(16) unsigned short hA[16*E_];    // 2KB swizzled bf16 h
  __shared__ __align__(16) float sC[RPB_*NC_];          // 12.1KB GEMM out
  __shared__ float sSc[RPB_*ND_];                       // 1.25KB attn scores
  __shared__ int sLM[RPB_*32];                          // 1KB last-med idx

  const int tid = threadIdx.x;
  const int w = tid >> 6, l = tid & 63;
  const int l15 = l & 15, l4 = l >> 4;
  const int rowbase = blockIdx.x * RPB_;
  const int row = rowbase + w;                          // this wave's row
  const int swz = ((( l>>3) ^ (w&7))<<3) + (l&7);       // hA swizzle for row w

  for (int i = tid; i < RPB_*NSTEP_; i += 512){
    int rr = i / NSTEP_, t = i - rr*NSTEP_;
    sLM[rr*32 + t] = (t==0) ? SOS_ : meds[(size_t)(rowbase+rr)*NM_ + (t-1)];
  }
  for (int i = tid; i < 8*E_; i += 512) hA[8*E_ + i] = 0;  // zero rows 8..15

  // ======== prologue: attention ctx (wave-private, 2-pass) ========
  float wd = aw[E_ + l];
  const int*   drow = dis   + (size_t)row*ND_;
  const float* mrow = dmask + (size_t)row*ND_;
  float mx = -INFINITY;
  #pragma unroll 8
  for (int n = 0; n < ND_; ++n){
    float d = dt[(size_t)drow[n]*E_ + l];
    float p = d * wd;
    #pragma unroll
    for (int m=1;m<64;m<<=1) p += __shfl_xor(p, m);
    float scn = p + mrow[n];                // uniform across lanes
    if (l == 0) sSc[w*ND_ + n] = scn;
    mx = fmaxf(mx, scn);
  }
  float ssum = 0.f;
  #pragma unroll 8
  for (int n = 0; n < ND_; ++n){
    float e = __expf(sSc[w*ND_ + n] - mx);  // uniform
    ssum += e;
    if (l == 0) sSc[w*ND_ + n] = e;
  }
  float inv = 1.f/ssum;
  float ctx = 0.f;
  #pragma unroll 8
  for (int n = 0; n < ND_; ++n)
    ctx = fmaf(sSc[w*ND_ + n], dt[(size_t)drow[n]*E_ + l], ctx);
  ctx *= inv;
  hA[w*E_ + swz] = f2bf(ctx);               // stage ctx as A-tile row w
  __syncthreads();

  // ======== prologue: gi = ctx @ W_ih_left^T + b_ih (+b_hh r,z) ========
  {
    const int ra = l15;
    short8 A00 = *(const short8*)&hA[ra*E_ + (((l4  ) ^ (ra&7))<<3)];
    short8 A01 = *(const short8*)&hA[ra*E_ + (((l4+4) ^ (ra&7))<<3)];
    #pragma unroll
    for (int j = 0; j < 2; ++j){
      int n = w + 8*j;
      if (n < 12){                          // 12 tiles cover 192 cols
        int c = n*16 + l15;
        short8 B0, B1;
        #pragma unroll
        for (int ks = 0; ks < 2; ++ks){
          const float* s = wih + (size_t)c*128 + ks*32 + l4*8;
          short8 f;
          #pragma unroll
          for (int jj=0;jj<8;jj++) f[jj] = (short)f2bf(s[jj]);
          if (ks==0) B0 = f; else B1 = f;
        }
        f32x4 cc = {0.f,0.f,0.f,0.f};
        cc = __builtin_amdgcn_mfma_f32_16x16x32_bf16(A00, B0, cc, 0,0,0);
        cc = __builtin_amdgcn_mfma_f32_16x16x32_bf16(A01, B1, cc, 0,0,0);
        if (l4 < 2){                        // rows 0..7 real
          float add = bih[c] + ((c < 128) ? bhh[c] : 0.f);
          #pragma unroll
          for (int i=0;i<4;i++) sC[(l4*4+i)*NC_ + c] = cc[i] + add;
        }
      }
    }
  }
  __syncthreads();
  float gia = sC[w*NC_ + l];
  float giz = sC[w*NC_ + l + 64];
  float gin = sC[w*NC_ + l + 128];
  float bhn = bhh[l + 128];
  const bool has2 = (l < 5);
  float wb0 = wob[l], wb1 = wob[l+64], wb2 = has2 ? wob[l+128] : 0.f;
  float hr = mt[SOS_*E_ + l];               // h0 = med_table[SOS]
  hA[w*E_ + swz] = f2bf(hr);                // re-init A-tile row w to h0
  __syncthreads();

  // ======== loop-invariant combined-weight B-fragments ========
  // wave w owns n-tiles {w, w+8, w+16}; cols: c<192 -> whh, else wo.
  short8 B0[3], B1[3];
  bool act[3];
  #pragma unroll
  for (int j = 0; j < 3; ++j){
    int n = w + 8*j;
    act[j] = (n*16 < NACT_);
    short8 z = {0,0,0,0,0,0,0,0};
    B0[j] = z; B1[j] = z;
    if (act[j]){
      int c = n*16 + l15;
      #pragma unroll
      for (int ks = 0; ks < 2; ++ks){
        int k0 = ks*32 + l4*8;
        float v[8];
        if (c < J3_){
          const float* s = whh + (size_t)c*E_ + k0;
          #pragma unroll
          for (int jj=0;jj<8;jj++) v[jj] = s[jj];
        } else if (c < 192+VO_){
          const float* s = wo + (size_t)(c-192)*E_ + k0;
          #pragma unroll
          for (int jj=0;jj<8;jj++) v[jj] = s[jj];
        } else {
          #pragma unroll
          for (int jj=0;jj<8;jj++) v[jj] = 0.f;
        }
        short8 f;
        #pragma unroll
        for (int jj=0;jj<8;jj++) f[jj] = (short)f2bf(v[jj]);
        if (ks==0) B0[j] = f; else B1[j] = f;
      }
    }
  }

  // ======== main loop ========
  for (int t = 0; t <= NSTEP_; ++t){
    const int ra = l15;
    short8 A00 = *(const short8*)&hA[ra*E_ + (((l4  ) ^ (ra&7))<<3)];
    short8 A01 = *(const short8*)&hA[ra*E_ + (((l4+4) ^ (ra&7))<<3)];
    #pragma unroll
    for (int j = 0; j < 3; ++j){
      if (act[j]){
        f32x4 cc = {0.f,0.f,0.f,0.f};
        cc = __builtin_amdgcn_mfma_f32_16x16x32_bf16(A00, B0[j], cc, 0,0,0);
        cc = __builtin_amdgcn_mfma_f32_16x16x32_bf16(A01, B1[j], cc, 0,0,0);
        int c = (w + 8*j)*16 + l15;
        if (l4 < 2){
          #pragma unroll
          for (int i=0;i<4;i++) sC[(l4*4+i)*NC_ + c] = cc[i];
        }
      }
    }
    __syncthreads();

    if (t < NSTEP_){
      // ---- pointwise GRU for row w (gh = sC cols 0..191) ----
      int lm = sLM[w*32 + t];
      const float* pr = pmed + (size_t)lm*J3_;
      float i_r = gia + pr[l]     + sC[w*NC_ + l];        // b_ih+b_hh folded
      float i_z = giz + pr[l+64]  + sC[w*NC_ + l+64];
      float i_n = gin + pr[l+128];
      float hnn = sC[w*NC_ + l+128] + bhn;
      float rg = sigmoidf_(i_r), zg = sigmoidf_(i_z);
      float ng = tanhf_(i_n + rg*hnn);
      hr = (1.f - zg)*ng + zg*hr;
      hA[w*E_ + swz] = f2bf(hr);
    }
    if (t >= 1){
      // ---- max-free log_softmax + store for step t-1 ----
      float l0  = sC[w*NC_ + 192 + l] + wb0;
      float l1  = sC[w*NC_ + 256 + l] + wb1;
      float l2v = sC[w*NC_ + 320 + l] + wb2;
      float s = __expf(l0) + __expf(l1) + (has2 ? __expf(l2v) : 0.f);
      #pragma unroll
      for (int mm=1;mm<64;mm<<=1) s += __shfl_xor(s, mm);
      float lg = __logf(s);
      size_t ob = ((size_t)row*NSTEP_ + (t-1))*VO_;
      out[ob + l]      = l0  - lg;
      out[ob + 64 + l] = l1  - lg;
      if (has2) out[ob + 128 + l] = l2v - lg;
    }
    __syncthreads();
  }
}

extern "C" void kernel_launch(void* const* d_in, const int* in_sizes, int n_in,
                              void* d_out, int out_size, void* d_ws, size_t ws_size,
                              hipStream_t stream){
  const int*   dis  = (const int*)  d_in[0];
  const int*   meds = (const int*)  d_in[2];
  const float* dmask= (const float*)d_in[3];
  const float* dt   = (const float*)d_in[6];
  const float* mt   = (const float*)d_in[7];
  const float* aw   = (const float*)d_in[8];
  const float* wih  = (const float*)d_in[10];
  const float* whh  = (const float*)d_in[11];
  const float* bih  = (const float*)d_in[12];
  const float* bhh  = (const float*)d_in[13];
  const float* wo   = (const float*)d_in[14];
  const float* wob  = (const float*)d_in[15];
  float* outp = (float*)d_out;
  float* pmed = (float*)d_ws;                     // 134*192 f32

  k_pmed<<<(134*J3_+255)/256, 256, 0, stream>>>(mt, wih, pmed);
  k_main<<<NROW_/RPB_, 512, 0, stream>>>(dis, dmask, dt, aw, meds,
                                         whh, bhh, wih, bih, wo, wob,
                                         mt, pmed, outp);
}